// Round 2
// baseline (2592.291 us; speedup 1.0000x reference)
//
#include <hip/hip_runtime.h>

typedef unsigned short u16;
typedef unsigned int   u32;
typedef __attribute__((ext_vector_type(8))) short  short8;
typedef __attribute__((ext_vector_type(8))) unsigned short ushort8;
typedef __attribute__((ext_vector_type(4))) float  f32x4;

#define NT 1024      // timesteps
#define NN 33        // nodes
#define NE 97        // edges

__device__ __forceinline__ float b2f(u16 u){ return __uint_as_float(((u32)u)<<16); }
__device__ __forceinline__ u16 f2b(float f){
    u32 x = __float_as_uint(f);
    return (u16)((x + 0x7fffu + ((x>>16)&1u)) >> 16);
}
__device__ __forceinline__ float sigm(float x){ return 1.f/(1.f+__expf(-x)); }
__device__ __forceinline__ float tanh_(float x){ float e=__expf(2.f*x); return 1.f - 2.f/(e+1.f); }

// ---------------------------------------------------------------------------
// dtype detection: view g1_wl (0.05*N(0,1)) as u32 words; low u16 as bf16 has
// exponent in [96,126] ~always iff data is bf16; fp32 mantissa noise ~12%.
// flag: 0 = bf16 inputs, 1 = fp32 inputs.
// ---------------------------------------------------------------------------
__global__ void detect_kernel(const u32* g1_wl_raw, int* flag){
    if (threadIdx.x==0 && blockIdx.x==0){
        int hits=0;
        for (int k=0;k<256;k++){
            u32 w = g1_wl_raw[k];
            u32 e = (w>>7)&0xffu;         // exponent of LOW u16 viewed as bf16
            if (e>=96u && e<=126u) hits++;
        }
        *flag = (hits>=160) ? 0 : 1;
    }
}

// canonicalize all 22 float tensors into one bf16 blob
struct ConvArgs { const void* src[22]; int n[22]; int off[22]; };
__global__ void convert_kernel(ConvArgs a, const int* flag, u16* blob){
    bool isf32 = (*flag)!=0;
    int stride = gridDim.x*blockDim.x;
    for (int s=0;s<22;s++){
        int n=a.n[s]; const void* sp=a.src[s]; u16* dp=blob+a.off[s];
        for (int i=blockIdx.x*blockDim.x+threadIdx.x; i<n; i+=stride)
            dp[i] = isf32 ? f2b(((const float*)sp)[i]) : ((const u16*)sp)[i];
    }
}

// canonical blob element offsets (all multiples of 8 for 16B-aligned rows)
#define CX      0
#define CEA     67584
#define CG1WL   67880
#define CG1WR   68904
#define CG1WE   69928
#define CG1ATT  71464
#define CG1B    71976
#define CG2WL   72488
#define CG2WR   334632
#define CG2WE   596776
#define CG2ATT  598312
#define CG2B    598824
#define CL1WIH  599336
#define CL1WHH  9250088
#define CL1BIH  9315624
#define CL1BHH  9316136
#define CL2WIH  9316648
#define CL2WHH  9349416
#define CL2BIH  9365800
#define CL2BHH  9366056
#define CFCW    9366312
#define CFCB    9366568
#define CBLOB_END 9366580

// ---------------------------------------------------------------------------
// setup: CSR by dst, ep1 = edge_attr@g1_we (97x512 f32), ep2 likewise,
// wlrt = [g2_wl^T ; g2_wr^T]  (1024 x 512 bf16, NT-ready)
// csr ints layout: [0..33]=off, [34..130]=eid, [131..227]=src, [228..324]=dst
// ---------------------------------------------------------------------------
__global__ void setup_kernel(const int* ei, const u16* ea,
                             const u16* g1_we, const u16* g2_we,
                             const u16* g2_wl, const u16* g2_wr,
                             int* csr, float* ep1, float* ep2, u16* wlrt)
{
    int tid = threadIdx.x;
    if (tid == 0) {
        int cnt[NN]; for (int n=0;n<NN;n++) cnt[n]=0;
        for (int e=0;e<NE;e++) cnt[ei[NE+e]]++;
        int off=0;
        for (int n=0;n<NN;n++){ csr[n]=off; off+=cnt[n]; }
        csr[NN]=off;
        int pos[NN]; for (int n=0;n<NN;n++) pos[n]=csr[n];
        for (int e=0;e<NE;e++){ int d=ei[NE+e]; csr[34+pos[d]]=e; pos[d]++; }
        for (int e=0;e<NE;e++){ csr[131+e]=ei[e]; csr[228+e]=ei[NE+e]; }
    }
    for (int i=tid; i<NE*512; i+=blockDim.x) {
        int e = i>>9, hc = i&511;
        float a0=b2f(ea[e*3]), a1=b2f(ea[e*3+1]), a2=b2f(ea[e*3+2]);
        ep1[i] = a0*b2f(g1_we[hc]) + a1*b2f(g1_we[512+hc]) + a2*b2f(g1_we[1024+hc]);
        ep2[i] = a0*b2f(g2_we[hc]) + a1*b2f(g2_we[512+hc]) + a2*b2f(g2_we[1024+hc]);
    }
    for (int i=tid; i<1024*512; i+=blockDim.x) {
        int c = i>>9, k = i&511;
        wlrt[i] = (c<512) ? g2_wl[k*512+c] : g2_wr[k*512+(c-512)];
    }
}

// ---------------------------------------------------------------------------
// GAT layer 1: one block per timestep. xl/xr recomputed on the fly (D_IN=2).
// h1[(t*33+n)*512 + hc] bf16
// ---------------------------------------------------------------------------
__global__ __launch_bounds__(256) void gat1_kernel(
    const u16* x, const u16* g1_wl, const u16* g1_wr, const u16* g1_att,
    const u16* g1_b, const float* ep1, const int* csr, u16* h1)
{
    __shared__ float wl[2][512], wr[2][512], att[512], bias[512];
    __shared__ float xt[2*NN];
    __shared__ float logits[NE*8];            // later alpha (in place)
    __shared__ float mmax[NN*8], den[NN*8];
    __shared__ int s_off[NN+1], s_eid[NE], s_src[NE], s_dst[NE];
    int t = blockIdx.x, tid = threadIdx.x;

    for (int i=tid;i<512;i+=256){
        wl[0][i]=b2f(g1_wl[i]);      wl[1][i]=b2f(g1_wl[512+i]);
        wr[0][i]=b2f(g1_wr[i]);      wr[1][i]=b2f(g1_wr[512+i]);
        att[i]=b2f(g1_att[i]);       bias[i]=b2f(g1_b[i]);
    }
    for (int i=tid;i<2*NN;i+=256) xt[i]=b2f(x[t*(2*NN)+i]);
    if (tid<NN+1) s_off[tid]=csr[tid];
    for (int i=tid;i<NE;i+=256){ s_eid[i]=csr[34+i]; s_src[i]=csr[131+i]; s_dst[i]=csr[228+i]; }
    __syncthreads();

    for (int i=tid; i<NE*8; i+=256) {           // logits
        int e=i>>3, h=i&7;
        int s=s_src[e], d=s_dst[e];
        float xs0=xt[s*2], xs1=xt[s*2+1], xd0=xt[d*2], xd1=xt[d*2+1];
        const float* epp = ep1 + e*512 + h*64;
        float acc=0.f;
        #pragma unroll 8
        for (int c=0;c<64;c++){
            int hc=h*64+c;
            float v = xs0*wl[0][hc] + xs1*wl[1][hc]
                    + xd0*wr[0][hc] + xd1*wr[1][hc] + epp[c];
            v = v>0.f ? v : 0.2f*v;
            acc += att[hc]*v;
        }
        logits[i]=acc;
    }
    __syncthreads();
    for (int i=tid; i<NN*8; i+=256) {           // per (dst,h) max & denom
        int n=i>>3, h=i&7;
        float m=-1e30f;
        for (int p=s_off[n]; p<s_off[n+1]; ++p){ float v=logits[s_eid[p]*8+h]; m=v>m?v:m; }
        float s=0.f;
        for (int p=s_off[n]; p<s_off[n+1]; ++p) s += __expf(logits[s_eid[p]*8+h]-m);
        mmax[i]=m; den[i]=s+1e-16f;
    }
    __syncthreads();
    for (int i=tid; i<NE*8; i+=256) {           // alpha in place
        int h=i&7, d=s_dst[i>>3];
        logits[i] = __expf(logits[i]-mmax[d*8+h]) / den[d*8+h];
    }
    __syncthreads();
    for (int i=tid; i<NN*512; i+=256) {         // out = sum alpha*xl(src) +b, elu
        int n=i>>9, hc=i&511, h=hc>>6;
        float acc=0.f;
        for (int p=s_off[n]; p<s_off[n+1]; ++p){
            int e=s_eid[p]; int s=s_src[e];
            float xlv = xt[s*2]*wl[0][hc] + xt[s*2+1]*wl[1][hc];
            acc += logits[e*8+h]*xlv;
        }
        acc += bias[hc];
        acc = acc>0.f ? acc : __expf(acc)-1.f;
        h1[(size_t)(t*NN+n)*512 + hc] = f2b(acc);
    }
}

// ---------------------------------------------------------------------------
// NT GEMM: C[M,N] = A[M,K] * B[N,K]^T, bf16 in, fp32 acc.
// 128x128 block tile, 4 waves each 64x64 (4x4 of 16x16x32 MFMA), BK=32.
// mode 0: store bf16; mode 1: store fp32 partials at kc*M*N.
// ---------------------------------------------------------------------------
__global__ __launch_bounds__(256) void gemm_nt(
    const u16* __restrict__ A, const u16* __restrict__ B, void* Cout,
    int M, int N, int K, int kChunk, int mode)
{
    __shared__ u16 lds_a[128*40];
    __shared__ u16 lds_b[128*40];
    const int nt = blockIdx.x, mt = blockIdx.y, kc = blockIdx.z;
    const int tid = threadIdx.x;
    const int wave = tid>>6, lane = tid&63;
    const int wm = (wave&1)*64, wn = (wave>>1)*64;
    const int l15 = lane&15, quad = lane>>4;
    const int srow = tid>>2, scol = (tid&3)*8;

    const u16* Ab = A + (size_t)mt*128*K;
    const u16* Bb = B + (size_t)nt*128*K;
    const int k0beg = kc*kChunk, k0end = k0beg + kChunk;

    f32x4 acc[4][4] = {};
    for (int k0 = k0beg; k0 < k0end; k0 += 32) {
        #pragma unroll
        for (int r = 0; r < 2; ++r) {
            int row = srow + r*64;
            *(ushort8*)&lds_a[row*40 + scol] = *(const ushort8*)&Ab[(size_t)row*K + k0 + scol];
            *(ushort8*)&lds_b[row*40 + scol] = *(const ushort8*)&Bb[(size_t)row*K + k0 + scol];
        }
        __syncthreads();
        short8 af[4], bfr[4];
        #pragma unroll
        for (int i=0;i<4;i++) af[i]  = *(const short8*)&lds_a[(wm + i*16 + l15)*40 + quad*8];
        #pragma unroll
        for (int j=0;j<4;j++) bfr[j] = *(const short8*)&lds_b[(wn + j*16 + l15)*40 + quad*8];
        #pragma unroll
        for (int i=0;i<4;i++)
            #pragma unroll
            for (int j=0;j<4;j++)
                acc[i][j] = __builtin_amdgcn_mfma_f32_16x16x32_bf16(af[i], bfr[j], acc[i][j], 0,0,0);
        __syncthreads();
    }
    if (mode == 0) {
        u16* Cb = (u16*)Cout;
        #pragma unroll
        for (int i=0;i<4;i++)
            #pragma unroll
            for (int j=0;j<4;j++)
                #pragma unroll
                for (int r=0;r<4;r++){
                    int row = mt*128 + wm + i*16 + quad*4 + r;
                    int col = nt*128 + wn + j*16 + l15;
                    Cb[(size_t)row*N + col] = f2b(acc[i][j][r]);
                }
    } else {
        float* Cb = (float*)Cout + (size_t)kc*M*N;
        #pragma unroll
        for (int i=0;i<4;i++)
            #pragma unroll
            for (int j=0;j<4;j++)
                #pragma unroll
                for (int r=0;r<4;r++){
                    int row = mt*128 + wm + i*16 + quad*4 + r;
                    int col = nt*128 + wn + j*16 + l15;
                    Cb[(size_t)row*N + col] = acc[i][j][r];
                }
    }
}

__global__ void reduce8_kernel(const float* part, float* out)
{
    int i = blockIdx.x*256 + threadIdx.x;   // 524288 total
    float s=0.f;
    #pragma unroll
    for (int k=0;k<8;k++) s += part[(size_t)k*524288 + i];
    out[i]=s;
}

// ---------------------------------------------------------------------------
// GAT layer 2 attention: one block per t. C = [xl2|xr2], row = t*33+n.
// Writes h2 PERMUTED [n][t][c] (= reference transpose+reshape seq layout).
// ---------------------------------------------------------------------------
__global__ __launch_bounds__(256) void gat2_kernel(
    const u16* C, const u16* g2_att, const u16* g2_b, const float* ep2,
    const int* csr, u16* h2)
{
    __shared__ u16 xl[NN*512];
    __shared__ float att[512], bias[512];
    __shared__ float part[NE*8];
    __shared__ float logit[NE], alpha[NE], mm[NN], dd[NN];
    __shared__ int s_off[NN+1], s_eid[NE], s_src[NE], s_dst[NE];
    int t = blockIdx.x, tid = threadIdx.x;

    for (int i=tid;i<512;i+=256){ att[i]=b2f(g2_att[i]); bias[i]=b2f(g2_b[i]); }
    if (tid<NN+1) s_off[tid]=csr[tid];
    for (int i=tid;i<NE;i+=256){ s_eid[i]=csr[34+i]; s_src[i]=csr[131+i]; s_dst[i]=csr[228+i]; }
    for (int i=tid; i<NN*64; i+=256){
        int n=i>>6, q=i&63;
        *(ushort8*)&xl[n*512+q*8] = *(const ushort8*)&C[(size_t)(t*NN+n)*1024 + q*8];
    }
    __syncthreads();

    for (int i=tid; i<NE*8; i+=256){            // partial logits
        int e=i>>3, q=i&7;
        int s=s_src[e], d=s_dst[e];
        const u16* xrp = C + (size_t)(t*NN+d)*1024 + 512 + q*64;
        const float* epp = ep2 + e*512 + q*64;
        const u16* xlp = xl + s*512 + q*64;
        float acc=0.f;
        #pragma unroll 8
        for (int c=0;c<64;c++){
            float v = b2f(xlp[c]) + b2f(xrp[c]) + epp[c];
            v = v>0.f ? v : 0.2f*v;
            acc += att[q*64+c]*v;
        }
        part[i]=acc;
    }
    __syncthreads();
    for (int i=tid;i<NE;i+=256){
        float s=0.f;
        #pragma unroll
        for (int q=0;q<8;q++) s+=part[i*8+q];
        logit[i]=s;
    }
    __syncthreads();
    for (int i=tid;i<NN;i+=256){
        float m=-1e30f;
        for (int p=s_off[i];p<s_off[i+1];++p){ float v=logit[s_eid[p]]; m=v>m?v:m; }
        float s=0.f;
        for (int p=s_off[i];p<s_off[i+1];++p) s+=__expf(logit[s_eid[p]]-m);
        mm[i]=m; dd[i]=s+1e-16f;
    }
    __syncthreads();
    for (int i=tid;i<NE;i+=256) alpha[i]=__expf(logit[i]-mm[s_dst[i]])/dd[s_dst[i]];
    __syncthreads();
    for (int i=tid;i<NN*512;i+=256){
        int n=i>>9, c=i&511;
        float acc=0.f;
        for (int p=s_off[n];p<s_off[n+1];++p){ int e=s_eid[p]; acc += alpha[e]*b2f(xl[s_src[e]*512+c]); }
        acc += bias[c];
        acc = acc>0.f ? acc : __expf(acc)-1.f;
        h2[(size_t)n*524288 + (size_t)t*512 + c] = f2b(acc);   // [n][t][c]
    }
}

// ---------------------------------------------------------------------------
// LSTM layer 1: single block, 512 threads; whh row in VGPRs, h via LDS.
// ---------------------------------------------------------------------------
__global__ __launch_bounds__(512) void lstm1_kernel(
    const float* __restrict__ pre1, const u16* __restrict__ whh,
    const u16* bih, const u16* bhh, u16* hs1)
{
    __shared__ float h_lds[128];
    __shared__ float z_lds[512];
    const int r = threadIdx.x;
    u32 w[64];
    const u32* wrow = (const u32*)(whh + r*128);
    #pragma unroll
    for (int k=0;k<64;k++) w[k]=wrow[k];
    const float bz = b2f(bih[r]) + b2f(bhh[r]);
    float c = 0.f;
    if (r < 128) h_lds[r] = 0.f;
    __syncthreads();
    float pcur = pre1[r];
    for (int t=0;t<1024;t++){
        float pnext = (t<1023) ? pre1[(t+1)*512 + r] : 0.f;
        float acc = pcur + bz;
        #pragma unroll
        for (int k=0;k<32;k++){
            float4 hv = *(const float4*)&h_lds[k*4];
            u32 w0=w[2*k], w1=w[2*k+1];
            acc += __uint_as_float((w0&0xffffu)<<16)*hv.x;
            acc += __uint_as_float(w0&0xffff0000u)*hv.y;
            acc += __uint_as_float((w1&0xffffu)<<16)*hv.z;
            acc += __uint_as_float(w1&0xffff0000u)*hv.w;
        }
        z_lds[r]=acc;
        __syncthreads();
        if (r<128){
            float zi=z_lds[r], zf=z_lds[128+r], zg=z_lds[256+r], zo=z_lds[384+r];
            c = sigm(zf)*c + sigm(zi)*tanh_(zg);
            float ho = sigm(zo)*tanh_(c);
            h_lds[r]=ho;
            hs1[t*128+r]=f2b(ho);
        }
        __syncthreads();
        pcur = pnext;
    }
}

// ---------------------------------------------------------------------------
// LSTM layer 2 + final FC; output dtype per flag (0=bf16, 1=fp32).
// ---------------------------------------------------------------------------
__global__ __launch_bounds__(256) void lstm2_kernel(
    const float* __restrict__ pre2, const u16* __restrict__ whh,
    const u16* bih, const u16* bhh, const u16* fc_w, const u16* fc_b,
    const int* flag, void* outv)
{
    __shared__ float h_lds[64];
    __shared__ float z_lds[256];
    const int r = threadIdx.x;
    u32 w[32];
    const u32* wrow = (const u32*)(whh + r*64);
    #pragma unroll
    for (int k=0;k<32;k++) w[k]=wrow[k];
    const float bz = b2f(bih[r]) + b2f(bhh[r]);
    float c = 0.f;
    if (r < 64) h_lds[r] = 0.f;
    __syncthreads();
    float pcur = pre2[r];
    for (int t=0;t<1024;t++){
        float pnext = (t<1023) ? pre2[(t+1)*256 + r] : 0.f;
        float acc = pcur + bz;
        #pragma unroll
        for (int k=0;k<16;k++){
            float4 hv = *(const float4*)&h_lds[k*4];
            u32 w0=w[2*k], w1=w[2*k+1];
            acc += __uint_as_float((w0&0xffffu)<<16)*hv.x;
            acc += __uint_as_float(w0&0xffff0000u)*hv.y;
            acc += __uint_as_float((w1&0xffffu)<<16)*hv.z;
            acc += __uint_as_float(w1&0xffff0000u)*hv.w;
        }
        z_lds[r]=acc;
        __syncthreads();
        if (r<64){
            float zi=z_lds[r], zf=z_lds[64+r], zg=z_lds[128+r], zo=z_lds[192+r];
            c = sigm(zf)*c + sigm(zi)*tanh_(zg);
            h_lds[r] = sigm(zo)*tanh_(c);
        }
        __syncthreads();
        pcur = pnext;
    }
    if (r<4){
        float acc = b2f(fc_b[r]);
        #pragma unroll
        for (int j=0;j<64;j++) acc += h_lds[j]*b2f(fc_w[r*64+j]);
        if (*flag) ((float*)outv)[r] = acc;
        else       ((u16*)outv)[r]  = f2b(acc);
    }
}

// ---------------------------------------------------------------------------
extern "C" void kernel_launch(void* const* d_in, const int* in_sizes, int n_in,
                              void* d_out, int out_size, void* d_ws, size_t ws_size,
                              hipStream_t stream) {
    const int* ei = (const int*)d_in[1];
    char* ws = (char*)d_ws;

    const size_t o_blob = 0;                                 // 18,733,184 B
    const size_t o_h    = 18733184;                          // 34,603,008
    const size_t o_C    = o_h    + 34603008;                 // 69,206,016
    const size_t o_wlrt = o_C    + 69206016;                 // 1,048,576
    const size_t o_ep1  = o_wlrt + 1048576;                  // 198,656
    const size_t o_ep2  = o_ep1  + 198656;                   // 198,656
    const size_t o_csr  = o_ep2  + 198656;                   // 2,048
    const size_t o_pre1 = o_csr  + 2048;                     // 2,097,152
    const size_t o_hs1  = o_pre1 + 2097152;                  // 262,144
    const size_t o_pre2 = o_hs1  + 262144;                   // 1,048,576

    u16*   blob  = (u16*)(ws + o_blob);
    u16*   h_buf = (u16*)(ws + o_h);
    u16*   Cbuf  = (u16*)(ws + o_C);
    u16*   wlrt  = (u16*)(ws + o_wlrt);
    float* ep1   = (float*)(ws + o_ep1);
    float* ep2   = (float*)(ws + o_ep2);
    int*   csr   = (int*)(ws + o_csr);
    int*   flag  = csr + 400;
    float* pre1  = (float*)(ws + o_pre1);
    u16*   hs1   = (u16*)(ws + o_hs1);
    float* pre2  = (float*)(ws + o_pre2);
    float* part  = (float*)(ws + o_C);   // overlays C after gat2 consumed it

    detect_kernel<<<1,64,0,stream>>>((const u32*)d_in[3], flag);

    ConvArgs ca;
    const int blob_off[22] = {CX,CEA,CG1WL,CG1WR,CG1WE,CG1ATT,CG1B,
                              CG2WL,CG2WR,CG2WE,CG2ATT,CG2B,
                              CL1WIH,CL1WHH,CL1BIH,CL1BHH,
                              CL2WIH,CL2WHH,CL2BIH,CL2BHH,CFCW,CFCB};
    const int in_idx[22]   = {0,2,3,4,5,6,7,8,9,10,11,12,13,14,15,16,17,18,19,20,21,22};
    for (int s=0;s<22;s++){
        ca.src[s]=d_in[in_idx[s]]; ca.n[s]=in_sizes[in_idx[s]]; ca.off[s]=blob_off[s];
    }
    convert_kernel<<<2048,256,0,stream>>>(ca, flag, blob);

    setup_kernel<<<1,256,0,stream>>>(ei, blob+CEA, blob+CG1WE, blob+CG2WE,
                                     blob+CG2WL, blob+CG2WR, csr, ep1, ep2, wlrt);
    gat1_kernel<<<NT,256,0,stream>>>(blob+CX, blob+CG1WL, blob+CG1WR, blob+CG1ATT,
                                     blob+CG1B, ep1, csr, h_buf);
    // xl2|xr2 = h1 @ [wl|wr]:  M=33792 N=1024 K=512
    gemm_nt<<<dim3(8,264,1),256,0,stream>>>(h_buf, wlrt, Cbuf, 33792, 1024, 512, 512, 0);
    gat2_kernel<<<NT,256,0,stream>>>(Cbuf, blob+CG2ATT, blob+CG2B, ep2, csr, h_buf);
    // pre1 = seq @ l1_wih^T: M=1024 N=512 K=16896, split-K=8
    gemm_nt<<<dim3(4,8,8),256,0,stream>>>(h_buf, blob+CL1WIH, part, 1024, 512, 16896, 2112, 1);
    reduce8_kernel<<<2048,256,0,stream>>>(part, pre1);
    lstm1_kernel<<<1,512,0,stream>>>(pre1, blob+CL1WHH, blob+CL1BIH, blob+CL1BHH, hs1);
    // pre2 = hs1 @ l2_wih^T: M=1024 N=256 K=128
    gemm_nt<<<dim3(2,8,1),256,0,stream>>>(hs1, blob+CL2WIH, pre2, 1024, 256, 128, 128, 1);
    lstm2_kernel<<<1,256,0,stream>>>(pre2, blob+CL2WHH, blob+CL2BIH, blob+CL2BHH,
                                     blob+CFCW, blob+CFCB, flag, d_out);
}

// Round 3
// 2033.448 us; speedup vs baseline: 1.2748x; 1.2748x over previous
//
#include <hip/hip_runtime.h>

typedef unsigned short u16;
typedef unsigned int   u32;
typedef __attribute__((ext_vector_type(8))) short  short8;
typedef __attribute__((ext_vector_type(8))) unsigned short ushort8;
typedef __attribute__((ext_vector_type(4))) float  f32x4;

#define NT 1024      // timesteps
#define NN 33        // nodes
#define NE 97        // edges

__device__ __forceinline__ float b2f(u16 u){ return __uint_as_float(((u32)u)<<16); }
__device__ __forceinline__ u16 f2b(float f){
    u32 x = __float_as_uint(f);
    return (u16)((x + 0x7fffu + ((x>>16)&1u)) >> 16);
}
__device__ __forceinline__ float sigm(float x){ return 1.f/(1.f+__expf(-x)); }
__device__ __forceinline__ float tanh_(float x){ float e=__expf(2.f*x); return 1.f - 2.f/(e+1.f); }

// ---------------------------------------------------------------------------
// dtype detection: low u16 of fp32 words is mantissa noise; of bf16-pair data
// it's a bf16 with exponent in [96,126] for 0.05*N(0,1). flag: 0=bf16, 1=fp32.
// ---------------------------------------------------------------------------
__global__ void detect_kernel(const u32* g1_wl_raw, int* flag){
    if (threadIdx.x==0 && blockIdx.x==0){
        int hits=0;
        for (int k=0;k<256;k++){
            u32 w = g1_wl_raw[k];
            u32 e = (w>>7)&0xffu;
            if (e>=96u && e<=126u) hits++;
        }
        *flag = (hits>=160) ? 0 : 1;
    }
}

struct ConvArgs { const void* src[22]; int n[22]; int off[22]; };
__global__ void convert_kernel(ConvArgs a, const int* flag, u16* blob){
    bool isf32 = (*flag)!=0;
    int stride = gridDim.x*blockDim.x;
    for (int s=0;s<22;s++){
        int n=a.n[s]; const void* sp=a.src[s]; u16* dp=blob+a.off[s];
        for (int i=blockIdx.x*blockDim.x+threadIdx.x; i<n; i+=stride)
            dp[i] = isf32 ? f2b(((const float*)sp)[i]) : ((const u16*)sp)[i];
    }
}

// canonical blob element offsets
#define CX      0
#define CEA     67584
#define CG1WL   67880
#define CG1WR   68904
#define CG1WE   69928
#define CG1ATT  71464
#define CG1B    71976
#define CG2WL   72488
#define CG2WR   334632
#define CG2WE   596776
#define CG2ATT  598312
#define CG2B    598824
#define CL1WIH  599336
#define CL1WHH  9250088
#define CL1BIH  9315624
#define CL1BHH  9316136
#define CL2WIH  9316648
#define CL2WHH  9349416
#define CL2BIH  9365800
#define CL2BHH  9366056
#define CFCW    9366312
#define CFCB    9366568

// ---------------------------------------------------------------------------
// setup: CSR by dst + ep1/ep2 edge projections. (wlrt moved out.)
// csr ints: [0..33]=off, [34..130]=eid, [131..227]=src, [228..324]=dst
// ---------------------------------------------------------------------------
__global__ void setup_kernel(const int* ei, const u16* ea,
                             const u16* g1_we, const u16* g2_we,
                             int* csr, float* ep1, float* ep2)
{
    int tid = threadIdx.x;
    if (tid == 0) {
        int cnt[NN]; for (int n=0;n<NN;n++) cnt[n]=0;
        for (int e=0;e<NE;e++) cnt[ei[NE+e]]++;
        int off=0;
        for (int n=0;n<NN;n++){ csr[n]=off; off+=cnt[n]; }
        csr[NN]=off;
        int pos[NN]; for (int n=0;n<NN;n++) pos[n]=csr[n];
        for (int e=0;e<NE;e++){ int d=ei[NE+e]; csr[34+pos[d]]=e; pos[d]++; }
        for (int e=0;e<NE;e++){ csr[131+e]=ei[e]; csr[228+e]=ei[NE+e]; }
    }
    for (int i=tid; i<NE*512; i+=blockDim.x) {
        int e = i>>9, hc = i&511;
        float a0=b2f(ea[e*3]), a1=b2f(ea[e*3+1]), a2=b2f(ea[e*3+2]);
        ep1[i] = a0*b2f(g1_we[hc]) + a1*b2f(g1_we[512+hc]) + a2*b2f(g1_we[1024+hc]);
        ep2[i] = a0*b2f(g2_we[hc]) + a1*b2f(g2_we[512+hc]) + a2*b2f(g2_we[1024+hc]);
    }
}

// wlrt = [g2_wl^T ; g2_wr^T] (1024 x 512), coalesced reads, scattered writes
__global__ void wlrt_kernel(const u16* g2_wl, const u16* g2_wr, u16* wlrt)
{
    int i = blockIdx.x*256 + threadIdx.x;     // 262144 total
    int k = i>>9, c = i&511;
    wlrt[c*512 + k]        = g2_wl[i];
    wlrt[(c+512)*512 + k]  = g2_wr[i];
}

// ---------------------------------------------------------------------------
// GAT layer 1: one block per timestep.
// ---------------------------------------------------------------------------
__global__ __launch_bounds__(256) void gat1_kernel(
    const u16* x, const u16* g1_wl, const u16* g1_wr, const u16* g1_att,
    const u16* g1_b, const float* ep1, const int* csr, u16* h1)
{
    __shared__ float wl[2][512], wr[2][512], att[512], bias[512];
    __shared__ float xt[2*NN];
    __shared__ float logits[NE*8];
    __shared__ float mmax[NN*8], den[NN*8];
    __shared__ int s_off[NN+1], s_eid[NE], s_src[NE], s_dst[NE];
    int t = blockIdx.x, tid = threadIdx.x;

    for (int i=tid;i<512;i+=256){
        wl[0][i]=b2f(g1_wl[i]);      wl[1][i]=b2f(g1_wl[512+i]);
        wr[0][i]=b2f(g1_wr[i]);      wr[1][i]=b2f(g1_wr[512+i]);
        att[i]=b2f(g1_att[i]);       bias[i]=b2f(g1_b[i]);
    }
    for (int i=tid;i<2*NN;i+=256) xt[i]=b2f(x[t*(2*NN)+i]);
    if (tid<NN+1) s_off[tid]=csr[tid];
    for (int i=tid;i<NE;i+=256){ s_eid[i]=csr[34+i]; s_src[i]=csr[131+i]; s_dst[i]=csr[228+i]; }
    __syncthreads();

    for (int i=tid; i<NE*8; i+=256) {
        int e=i>>3, h=i&7;
        int s=s_src[e], d=s_dst[e];
        float xs0=xt[s*2], xs1=xt[s*2+1], xd0=xt[d*2], xd1=xt[d*2+1];
        const float* epp = ep1 + e*512 + h*64;
        float acc=0.f;
        #pragma unroll 8
        for (int c=0;c<64;c++){
            int hc=h*64+c;
            float v = xs0*wl[0][hc] + xs1*wl[1][hc]
                    + xd0*wr[0][hc] + xd1*wr[1][hc] + epp[c];
            v = v>0.f ? v : 0.2f*v;
            acc += att[hc]*v;
        }
        logits[i]=acc;
    }
    __syncthreads();
    for (int i=tid; i<NN*8; i+=256) {
        int n=i>>3, h=i&7;
        float m=-1e30f;
        for (int p=s_off[n]; p<s_off[n+1]; ++p){ float v=logits[s_eid[p]*8+h]; m=v>m?v:m; }
        float s=0.f;
        for (int p=s_off[n]; p<s_off[n+1]; ++p) s += __expf(logits[s_eid[p]*8+h]-m);
        mmax[i]=m; den[i]=s+1e-16f;
    }
    __syncthreads();
    for (int i=tid; i<NE*8; i+=256) {
        int h=i&7, d=s_dst[i>>3];
        logits[i] = __expf(logits[i]-mmax[d*8+h]) / den[d*8+h];
    }
    __syncthreads();
    for (int i=tid; i<NN*512; i+=256) {
        int n=i>>9, hc=i&511, h=hc>>6;
        float acc=0.f;
        for (int p=s_off[n]; p<s_off[n+1]; ++p){
            int e=s_eid[p]; int s=s_src[e];
            float xlv = xt[s*2]*wl[0][hc] + xt[s*2+1]*wl[1][hc];
            acc += logits[e*8+h]*xlv;
        }
        acc += bias[hc];
        acc = acc>0.f ? acc : __expf(acc)-1.f;
        h1[(size_t)(t*NN+n)*512 + hc] = f2b(acc);
    }
}

// ---------------------------------------------------------------------------
// NT GEMM: C[M,N] = A[M,K] * B[N,K]^T, bf16 in, fp32 acc. 128x128 tile.
// ---------------------------------------------------------------------------
__global__ __launch_bounds__(256) void gemm_nt(
    const u16* __restrict__ A, const u16* __restrict__ B, void* Cout,
    int M, int N, int K, int kChunk, int mode)
{
    __shared__ u16 lds_a[128*40];
    __shared__ u16 lds_b[128*40];
    const int nt = blockIdx.x, mt = blockIdx.y, kc = blockIdx.z;
    const int tid = threadIdx.x;
    const int wave = tid>>6, lane = tid&63;
    const int wm = (wave&1)*64, wn = (wave>>1)*64;
    const int l15 = lane&15, quad = lane>>4;
    const int srow = tid>>2, scol = (tid&3)*8;

    const u16* Ab = A + (size_t)mt*128*K;
    const u16* Bb = B + (size_t)nt*128*K;
    const int k0beg = kc*kChunk, k0end = k0beg + kChunk;

    f32x4 acc[4][4] = {};
    for (int k0 = k0beg; k0 < k0end; k0 += 32) {
        #pragma unroll
        for (int r = 0; r < 2; ++r) {
            int row = srow + r*64;
            *(ushort8*)&lds_a[row*40 + scol] = *(const ushort8*)&Ab[(size_t)row*K + k0 + scol];
            *(ushort8*)&lds_b[row*40 + scol] = *(const ushort8*)&Bb[(size_t)row*K + k0 + scol];
        }
        __syncthreads();
        short8 af[4], bfr[4];
        #pragma unroll
        for (int i=0;i<4;i++) af[i]  = *(const short8*)&lds_a[(wm + i*16 + l15)*40 + quad*8];
        #pragma unroll
        for (int j=0;j<4;j++) bfr[j] = *(const short8*)&lds_b[(wn + j*16 + l15)*40 + quad*8];
        #pragma unroll
        for (int i=0;i<4;i++)
            #pragma unroll
            for (int j=0;j<4;j++)
                acc[i][j] = __builtin_amdgcn_mfma_f32_16x16x32_bf16(af[i], bfr[j], acc[i][j], 0,0,0);
        __syncthreads();
    }
    if (mode == 0) {
        u16* Cb = (u16*)Cout;
        #pragma unroll
        for (int i=0;i<4;i++)
            #pragma unroll
            for (int j=0;j<4;j++)
                #pragma unroll
                for (int r=0;r<4;r++){
                    int row = mt*128 + wm + i*16 + quad*4 + r;
                    int col = nt*128 + wn + j*16 + l15;
                    Cb[(size_t)row*N + col] = f2b(acc[i][j][r]);
                }
    } else {
        float* Cb = (float*)Cout + (size_t)kc*M*N;
        #pragma unroll
        for (int i=0;i<4;i++)
            #pragma unroll
            for (int j=0;j<4;j++)
                #pragma unroll
                for (int r=0;r<4;r++){
                    int row = mt*128 + wm + i*16 + quad*4 + r;
                    int col = nt*128 + wn + j*16 + l15;
                    Cb[(size_t)row*N + col] = acc[i][j][r];
                }
    }
}

__global__ void reduce8_kernel(const float* part, float* out)
{
    int i = blockIdx.x*256 + threadIdx.x;   // 524288 total
    float s=0.f;
    #pragma unroll
    for (int k=0;k<8;k++) s += part[(size_t)k*524288 + i];
    out[i]=s;
}

// ---------------------------------------------------------------------------
// GAT layer 2 attention; writes h2 PERMUTED [n][t][c].
// ---------------------------------------------------------------------------
__global__ __launch_bounds__(256) void gat2_kernel(
    const u16* C, const u16* g2_att, const u16* g2_b, const float* ep2,
    const int* csr, u16* h2)
{
    __shared__ u16 xl[NN*512];
    __shared__ float att[512], bias[512];
    __shared__ float part[NE*8];
    __shared__ float logit[NE], alpha[NE], mm[NN], dd[NN];
    __shared__ int s_off[NN+1], s_eid[NE], s_src[NE], s_dst[NE];
    int t = blockIdx.x, tid = threadIdx.x;

    for (int i=tid;i<512;i+=256){ att[i]=b2f(g2_att[i]); bias[i]=b2f(g2_b[i]); }
    if (tid<NN+1) s_off[tid]=csr[tid];
    for (int i=tid;i<NE;i+=256){ s_eid[i]=csr[34+i]; s_src[i]=csr[131+i]; s_dst[i]=csr[228+i]; }
    for (int i=tid; i<NN*64; i+=256){
        int n=i>>6, q=i&63;
        *(ushort8*)&xl[n*512+q*8] = *(const ushort8*)&C[(size_t)(t*NN+n)*1024 + q*8];
    }
    __syncthreads();

    for (int i=tid; i<NE*8; i+=256){
        int e=i>>3, q=i&7;
        int s=s_src[e], d=s_dst[e];
        const u16* xrp = C + (size_t)(t*NN+d)*1024 + 512 + q*64;
        const float* epp = ep2 + e*512 + q*64;
        const u16* xlp = xl + s*512 + q*64;
        float acc=0.f;
        #pragma unroll 8
        for (int c=0;c<64;c++){
            float v = b2f(xlp[c]) + b2f(xrp[c]) + epp[c];
            v = v>0.f ? v : 0.2f*v;
            acc += att[q*64+c]*v;
        }
        part[i]=acc;
    }
    __syncthreads();
    for (int i=tid;i<NE;i+=256){
        float s=0.f;
        #pragma unroll
        for (int q=0;q<8;q++) s+=part[i*8+q];
        logit[i]=s;
    }
    __syncthreads();
    for (int i=tid;i<NN;i+=256){
        float m=-1e30f;
        for (int p=s_off[i];p<s_off[i+1];++p){ float v=logit[s_eid[p]]; m=v>m?v:m; }
        float s=0.f;
        for (int p=s_off[i];p<s_off[i+1];++p) s+=__expf(logit[s_eid[p]]-m);
        mm[i]=m; dd[i]=s+1e-16f;
    }
    __syncthreads();
    for (int i=tid;i<NE;i+=256) alpha[i]=__expf(logit[i]-mm[s_dst[i]])/dd[s_dst[i]];
    __syncthreads();
    for (int i=tid;i<NN*512;i+=256){
        int n=i>>9, c=i&511;
        float acc=0.f;
        for (int p=s_off[n];p<s_off[n+1];++p){ int e=s_eid[p]; acc += alpha[e]*b2f(xl[s_src[e]*512+c]); }
        acc += bias[c];
        acc = acc>0.f ? acc : __expf(acc)-1.f;
        h2[(size_t)n*524288 + (size_t)t*512 + c] = f2b(acc);
    }
}

// ---------------------------------------------------------------------------
// LSTM layer 1: single block, 512 threads; whh row pre-unpacked to f32 VGPRs,
// f32x4 elementwise-fma (v_pk_fma_f32), h broadcast via LDS float4 reads.
// ---------------------------------------------------------------------------
__global__ __launch_bounds__(512,2) void lstm1_kernel(
    const float* __restrict__ pre1, const u16* __restrict__ whh,
    const u16* bih, const u16* bhh, u16* hs1)
{
    __shared__ float h_lds[128];
    __shared__ float z_lds[512];
    const int r = threadIdx.x;
    f32x4 wv[32];
    const u32* wrow = (const u32*)(whh + r*128);
    #pragma unroll
    for (int j=0;j<32;j++){
        u32 w0=wrow[2*j], w1=wrow[2*j+1];
        wv[j][0]=__uint_as_float((w0&0xffffu)<<16);
        wv[j][1]=__uint_as_float(w0&0xffff0000u);
        wv[j][2]=__uint_as_float((w1&0xffffu)<<16);
        wv[j][3]=__uint_as_float(w1&0xffff0000u);
    }
    const float bz = b2f(bih[r]) + b2f(bhh[r]);
    float c = 0.f;
    if (r < 128) h_lds[r] = 0.f;
    __syncthreads();
    float pcur = pre1[r];
    const f32x4* h4 = (const f32x4*)h_lds;
    for (int t=0;t<1024;t++){
        float pnext = (t<1023) ? pre1[(t+1)*512 + r] : 0.f;
        f32x4 aa = {0.f,0.f,0.f,0.f}, ab = {0.f,0.f,0.f,0.f};
        #pragma unroll
        for (int j=0;j<32;j+=2){
            aa = __builtin_elementwise_fma(wv[j],   h4[j],   aa);
            ab = __builtin_elementwise_fma(wv[j+1], h4[j+1], ab);
        }
        aa = aa + ab;
        z_lds[r] = pcur + bz + ((aa[0]+aa[1]) + (aa[2]+aa[3]));
        __syncthreads();
        if (r<128){
            float zi=z_lds[r], zf=z_lds[128+r], zg=z_lds[256+r], zo=z_lds[384+r];
            c = sigm(zf)*c + sigm(zi)*tanh_(zg);
            float ho = sigm(zo)*tanh_(c);
            h_lds[r]=ho;
            hs1[t*128+r]=f2b(ho);
        }
        __syncthreads();
        pcur = pnext;
    }
}

// ---------------------------------------------------------------------------
// LSTM layer 2 + final FC; f32x4 weights in VGPRs; output dtype per flag.
// ---------------------------------------------------------------------------
__global__ __launch_bounds__(256) void lstm2_kernel(
    const float* __restrict__ pre2, const u16* __restrict__ whh,
    const u16* bih, const u16* bhh, const u16* fc_w, const u16* fc_b,
    const int* flag, void* outv)
{
    __shared__ float h_lds[64];
    __shared__ float z_lds[256];
    const int r = threadIdx.x;
    f32x4 wv[16];
    const u32* wrow = (const u32*)(whh + r*64);
    #pragma unroll
    for (int j=0;j<16;j++){
        u32 w0=wrow[2*j], w1=wrow[2*j+1];
        wv[j][0]=__uint_as_float((w0&0xffffu)<<16);
        wv[j][1]=__uint_as_float(w0&0xffff0000u);
        wv[j][2]=__uint_as_float((w1&0xffffu)<<16);
        wv[j][3]=__uint_as_float(w1&0xffff0000u);
    }
    const float bz = b2f(bih[r]) + b2f(bhh[r]);
    float c = 0.f;
    if (r < 64) h_lds[r] = 0.f;
    __syncthreads();
    float pcur = pre2[r];
    const f32x4* h4 = (const f32x4*)h_lds;
    for (int t=0;t<1024;t++){
        float pnext = (t<1023) ? pre2[(t+1)*256 + r] : 0.f;
        f32x4 aa = {0.f,0.f,0.f,0.f}, ab = {0.f,0.f,0.f,0.f};
        #pragma unroll
        for (int j=0;j<16;j+=2){
            aa = __builtin_elementwise_fma(wv[j],   h4[j],   aa);
            ab = __builtin_elementwise_fma(wv[j+1], h4[j+1], ab);
        }
        aa = aa + ab;
        z_lds[r] = pcur + bz + ((aa[0]+aa[1]) + (aa[2]+aa[3]));
        __syncthreads();
        if (r<64){
            float zi=z_lds[r], zf=z_lds[64+r], zg=z_lds[128+r], zo=z_lds[192+r];
            c = sigm(zf)*c + sigm(zi)*tanh_(zg);
            h_lds[r] = sigm(zo)*tanh_(c);
        }
        __syncthreads();
        pcur = pnext;
    }
    if (r<4){
        float acc = b2f(fc_b[r]);
        #pragma unroll
        for (int j=0;j<64;j++) acc += h_lds[j]*b2f(fc_w[r*64+j]);
        if (*flag) ((float*)outv)[r] = acc;
        else       ((u16*)outv)[r]  = f2b(acc);
    }
}

// ---------------------------------------------------------------------------
extern "C" void kernel_launch(void* const* d_in, const int* in_sizes, int n_in,
                              void* d_out, int out_size, void* d_ws, size_t ws_size,
                              hipStream_t stream) {
    const int* ei = (const int*)d_in[1];
    char* ws = (char*)d_ws;

    const size_t o_blob = 0;
    const size_t o_h    = 18733184;
    const size_t o_C    = o_h    + 34603008;
    const size_t o_wlrt = o_C    + 69206016;
    const size_t o_ep1  = o_wlrt + 1048576;
    const size_t o_ep2  = o_ep1  + 198656;
    const size_t o_csr  = o_ep2  + 198656;
    const size_t o_pre1 = o_csr  + 2048;
    const size_t o_hs1  = o_pre1 + 2097152;
    const size_t o_pre2 = o_hs1  + 262144;

    u16*   blob  = (u16*)(ws + o_blob);
    u16*   h_buf = (u16*)(ws + o_h);
    u16*   Cbuf  = (u16*)(ws + o_C);
    u16*   wlrt  = (u16*)(ws + o_wlrt);
    float* ep1   = (float*)(ws + o_ep1);
    float* ep2   = (float*)(ws + o_ep2);
    int*   csr   = (int*)(ws + o_csr);
    int*   flag  = csr + 400;
    float* pre1  = (float*)(ws + o_pre1);
    u16*   hs1   = (u16*)(ws + o_hs1);
    float* pre2  = (float*)(ws + o_pre2);
    float* part  = (float*)(ws + o_C);

    detect_kernel<<<1,64,0,stream>>>((const u32*)d_in[3], flag);

    ConvArgs ca;
    const int blob_off[22] = {CX,CEA,CG1WL,CG1WR,CG1WE,CG1ATT,CG1B,
                              CG2WL,CG2WR,CG2WE,CG2ATT,CG2B,
                              CL1WIH,CL1WHH,CL1BIH,CL1BHH,
                              CL2WIH,CL2WHH,CL2BIH,CL2BHH,CFCW,CFCB};
    const int in_idx[22]   = {0,2,3,4,5,6,7,8,9,10,11,12,13,14,15,16,17,18,19,20,21,22};
    for (int s=0;s<22;s++){
        ca.src[s]=d_in[in_idx[s]]; ca.n[s]=in_sizes[in_idx[s]]; ca.off[s]=blob_off[s];
    }
    convert_kernel<<<2048,256,0,stream>>>(ca, flag, blob);

    setup_kernel<<<1,256,0,stream>>>(ei, blob+CEA, blob+CG1WE, blob+CG2WE, csr, ep1, ep2);
    wlrt_kernel<<<1024,256,0,stream>>>(blob+CG2WL, blob+CG2WR, wlrt);
    gat1_kernel<<<NT,256,0,stream>>>(blob+CX, blob+CG1WL, blob+CG1WR, blob+CG1ATT,
                                     blob+CG1B, ep1, csr, h_buf);
    gemm_nt<<<dim3(8,264,1),256,0,stream>>>(h_buf, wlrt, Cbuf, 33792, 1024, 512, 512, 0);
    gat2_kernel<<<NT,256,0,stream>>>(Cbuf, blob+CG2ATT, blob+CG2B, ep2, csr, h_buf);
    gemm_nt<<<dim3(4,8,8),256,0,stream>>>(h_buf, blob+CL1WIH, part, 1024, 512, 16896, 2112, 1);
    reduce8_kernel<<<2048,256,0,stream>>>(part, pre1);
    lstm1_kernel<<<1,512,0,stream>>>(pre1, blob+CL1WHH, blob+CL1BIH, blob+CL1BHH, hs1);
    gemm_nt<<<dim3(2,8,1),256,0,stream>>>(hs1, blob+CL2WIH, pre2, 1024, 256, 128, 128, 1);
    lstm2_kernel<<<1,256,0,stream>>>(pre2, blob+CL2WHH, blob+CL2BIH, blob+CL2BHH,
                                     blob+CFCW, blob+CFCB, flag, d_out);
}